// Round 2
// baseline (387.534 us; speedup 1.0000x reference)
//
#include <hip/hip_runtime.h>
#include <math.h>

// Problem constants (from reference setup_inputs)
#define NB   8192   // batch
#define NC   3755   // chars
#define NR   214    // radicals
#define NS   13     // structure classes
#define NSC  30     // stroke-count bins
#define NST  6      // stroke types
#define NH   64     // hidden
#define KTOP 20     // top_k
#define NT   256    // threads per block
#define EPT  15     // ceil(NC / NT) elements per thread

#define NBIN 1024   // histogram bins = top 10 bits of sort key (sign+exp+1 mant)
#define CAP  512    // candidate buffer capacity (typical M ~ 85 for N(0,1) rows)

// monotonic float -> uint transform (ascending float => ascending unsigned key)
__device__ __forceinline__ unsigned sortkey(float x) {
    unsigned u = __float_as_uint(x);
    return (u & 0x80000000u) ? ~u : (u | 0x80000000u);
}

__global__ __launch_bounds__(NT) void reranker_kernel(
    const float* __restrict__ char_logits,     // (B, C)
    const float* __restrict__ radical_logits,  // (B, R)
    const float* __restrict__ structure,       // (B, S)
    const float* __restrict__ stroke_count,    // (B, NSC)
    const float* __restrict__ stroke_types,    // (B, NST)
    const int*   __restrict__ radical_mask,    // (C, R)
    const int*   __restrict__ structure_label, // (C,)
    const int*   __restrict__ stroke_count_label, // (C,)
    const float* __restrict__ stroke_type_sig, // (C, NST)
    const float* __restrict__ W1,              // (6, H)
    const float* __restrict__ b1,              // (H,)
    const float* __restrict__ W2,              // (H, 1)
    const float* __restrict__ b2,              // (1,)
    const float* __restrict__ rw,              // scalar
    float*       __restrict__ out)             // (B, C)
{
    const int b    = blockIdx.x;
    const int tid  = threadIdx.x;
    const int lane = tid & 63;
    const int wave = tid >> 6;

    __shared__ int   hist[NBIN];         // 4 KB histogram for radix-style select
    __shared__ float cand_v[CAP];        // compacted top-candidate values
    __shared__ int   cand_i[CAP];        // and indices
    __shared__ int   s_cnt[2];           // [0] candidate count, [1] threshold bin
    __shared__ float s_red8[8];          // wave partials (maxes, then sums)
    __shared__ float s_topval[KTOP];
    __shared__ int   s_topidx[KTOP];
    __shared__ float s_probs[NR];        // sigmoid(radical_logits row)
    __shared__ float s_struct[NS];       // softmax(structure row)
    __shared__ float s_pred[NST];        // normalized stroke_types row
    __shared__ float s_feats[KTOP][6];
    __shared__ float s_misc[4];          // 0: sumexp, 1: total radical prob, 2: stroke_pred

    const size_t rowOff = (size_t)b * NC;

    // ---- load row into registers, pass-through copy to out ----
    float v[EPT];
#pragma unroll
    for (int t = 0; t < EPT; ++t) {
        int idx = tid + t * NT;
        float x = -INFINITY;
        if (idx < NC) {
            x = char_logits[rowOff + idx];
            out[rowOff + idx] = x;
        }
        v[t] = x;
    }

    // wave-level max (value only; needed as scan start + softmax max)
    float lm = -INFINITY;
#pragma unroll
    for (int t = 0; t < EPT; ++t) lm = fmaxf(lm, v[t]);
#pragma unroll
    for (int off = 32; off > 0; off >>= 1) lm = fmaxf(lm, __shfl_down(lm, off));
    if (lane == 0) s_red8[wave] = lm;
    if (tid == 0)  s_cnt[0] = 0;

    // ---- exact top-K via histogram select ----
    // Attempt 1 pre-filters x >= 1.0 (key 0xBF800000): for N(0,1) rows only
    // ~600/3755 values histogram -> negligible LDS-atomic contention. If a row
    // has <KTOP values >= 1.0, attempt 2 re-histograms everything (exactness
    // guaranteed for any input).
    unsigned floork = 0xBF800000u;
    int B0 = -1;
    for (int attempt = 0; attempt < 2 && B0 < 0; ++attempt) {
        for (int i = tid; i < NBIN; i += NT) hist[i] = 0;
        __syncthreads();
#pragma unroll
        for (int t = 0; t < EPT; ++t) {
            int idx = tid + t * NT;
            if (idx < NC) {
                unsigned k = sortkey(v[t]);
                if (k >= floork) atomicAdd(&hist[k >> 22], 1);
            }
        }
        __syncthreads();
        if (tid == 0) {
            float rm = fmaxf(fmaxf(s_red8[0], s_red8[1]), fmaxf(s_red8[2], s_red8[3]));
            int bb  = (int)(sortkey(rm) >> 22);
            int fb  = (int)(floork >> 22);
            int cum = 0;
            while (bb >= fb) {                 // ~5-8 iterations for this data
                cum += hist[bb];
                if (cum >= KTOP) break;
                --bb;
            }
            s_cnt[1] = (cum >= KTOP) ? bb : -1;
        }
        __syncthreads();
        B0 = s_cnt[1];
        floork = 0u;
    }

    // compact all elements in bins >= B0 (superset of the true top-K)
#pragma unroll
    for (int t = 0; t < EPT; ++t) {
        int idx = tid + t * NT;
        if (idx < NC) {
            unsigned k = sortkey(v[t]);
            if ((int)(k >> 22) >= B0) {
                int p = atomicAdd(&s_cnt[0], 1);
                if (p < CAP) { cand_v[p] = v[t]; cand_i[p] = idx; }
            }
        }
    }
    __syncthreads();

    // exact rank selection among M candidates (val desc, index asc — matches
    // jax.lax.top_k tie-breaking). Ranks are unique, so no write conflicts.
    int M = s_cnt[0]; if (M > CAP) M = CAP;
    for (int c = tid; c < M; c += NT) {
        float cv = cand_v[c]; int ci = cand_i[c];
        int rank = 0;
        for (int j = 0; j < M; ++j) {
            float ov = cand_v[j];
            rank += (ov > cv || (ov == cv && cand_i[j] < ci)) ? 1 : 0;
        }
        if (rank < KTOP) { s_topval[rank] = cv; s_topidx[rank] = ci; }
    }
    __syncthreads();

    const float rowmax = s_topval[0];

    // ---- softmax denominator (v[] intact; padding is -inf -> exp = 0) ----
    float le = 0.f;
#pragma unroll
    for (int t = 0; t < EPT; ++t) le += expf(v[t] - rowmax);
#pragma unroll
    for (int off = 32; off > 0; off >>= 1) le += __shfl_down(le, off);

    // ---- radical sigmoid probs + their sum ----
    float p = 0.f;
    if (tid < NR) {
        float x = radical_logits[(size_t)b * NR + tid];
        p = 1.f / (1.f + expf(-x));
        s_probs[tid] = p;
    }
#pragma unroll
    for (int off = 32; off > 0; off >>= 1) p += __shfl_down(p, off);

    if (lane == 0) { s_red8[wave] = le; s_red8[4 + wave] = p; }
    __syncthreads();

    if (tid == 0) {
        s_misc[0] = s_red8[0] + s_red8[1] + s_red8[2] + s_red8[3];
        s_misc[1] = s_red8[4] + s_red8[5] + s_red8[6] + s_red8[7];
    } else if (tid == 64) {
        // structure softmax (13)
        float sv[NS]; float m = -INFINITY;
#pragma unroll
        for (int i = 0; i < NS; ++i) { sv[i] = structure[(size_t)b * NS + i]; m = fmaxf(m, sv[i]); }
        float s = 0.f;
#pragma unroll
        for (int i = 0; i < NS; ++i) { sv[i] = expf(sv[i] - m); s += sv[i]; }
        float inv = 1.f / s;
#pragma unroll
        for (int i = 0; i < NS; ++i) s_struct[i] = sv[i] * inv;
    } else if (tid == 128) {
        // stroke-count argmax (first max wins)
        float bv = -INFINITY; int bi = 0;
#pragma unroll
        for (int i = 0; i < NSC; ++i) {
            float x = stroke_count[(size_t)b * NSC + i];
            if (x > bv) { bv = x; bi = i; }
        }
        s_misc[2] = (float)bi;
    } else if (tid == 192) {
        // normalized stroke_types row
        float t6[NST]; float ss = 0.f;
#pragma unroll
        for (int i = 0; i < NST; ++i) { t6[i] = stroke_types[(size_t)b * NST + i]; ss += t6[i] * t6[i]; }
        float inv = 1.f / fmaxf(sqrtf(ss), 1e-12f);
#pragma unroll
        for (int i = 0; i < NST; ++i) s_pred[i] = t6[i] * inv;
    }
    __syncthreads();

    const float sumexp = s_misc[0];
    const float total  = s_misc[1];
    const float spred  = s_misc[2];

    // ---- features: wave w handles candidates w, w+4, ... ----
    for (int k = wave; k < KTOP; k += 4) {
        int ci = s_topidx[k];
        const int* mrow = radical_mask + (size_t)ci * NR;
        float det = 0.f, cnt = 0.f;
        for (int r = lane; r < NR; r += 64) {
            float m = (float)mrow[r];
            det += s_probs[r] * m;
            cnt += m;
        }
#pragma unroll
        for (int off = 32; off > 0; off >>= 1) {
            det += __shfl_down(det, off);
            cnt += __shfl_down(cnt, off);
        }
        if (lane == 0) {
            float f1 = det / fmaxf(cnt, 1.f);
            float f2 = (total - det) / fmaxf(total, 1e-6f);
            float f3 = s_struct[structure_label[ci]];
            float f4 = fabsf(spred - (float)stroke_count_label[ci]) * (1.f / 29.f);
            // f5: zero-masked cosine
            float sig[NST]; float ss = 0.f;
#pragma unroll
            for (int i = 0; i < NST; ++i) { sig[i] = stroke_type_sig[(size_t)ci * NST + i]; ss += sig[i] * sig[i]; }
            float nrm = sqrtf(ss);
            float has = (nrm > 1e-6f) ? 1.f : 0.f;
            float add = 1e-8f * (1.f - has);
            float ss2 = 0.f;
#pragma unroll
            for (int i = 0; i < NST; ++i) { sig[i] += add; ss2 += sig[i] * sig[i]; }
            float inv = 1.f / fmaxf(sqrtf(ss2), 1e-12f);
            float dot = 0.f;
#pragma unroll
            for (int i = 0; i < NST; ++i) dot += s_pred[i] * sig[i] * inv;
            float f5 = dot * has;
            float f6 = expf(s_topval[k] - rowmax) / sumexp;
            s_feats[k][0] = f1; s_feats[k][1] = f2; s_feats[k][2] = f3;
            s_feats[k][3] = f4; s_feats[k][4] = f5; s_feats[k][5] = f6;
        }
    }
    __syncthreads();

    // ---- MLP + scatter: lane = hidden unit (H == 64) ----
    const float w = rw[0];
    for (int k = wave; k < KTOP; k += 4) {
        float f0 = s_feats[k][0], f1 = s_feats[k][1], f2 = s_feats[k][2];
        float f3 = s_feats[k][3], f4 = s_feats[k][4], f5 = s_feats[k][5];
        float acc = b1[lane];
        acc += f0 * W1[0 * NH + lane];
        acc += f1 * W1[1 * NH + lane];
        acc += f2 * W1[2 * NH + lane];
        acc += f3 * W1[3 * NH + lane];
        acc += f4 * W1[4 * NH + lane];
        acc += f5 * W1[5 * NH + lane];
        float h = fmaxf(acc, 0.f);
        float part = h * W2[lane];
#pragma unroll
        for (int off = 32; off > 0; off >>= 1) part += __shfl_down(part, off);
        if (lane == 0) {
            float score = part + b2[0];
            out[rowOff + s_topidx[k]] = s_topval[k] + w * score;
        }
    }
}

extern "C" void kernel_launch(void* const* d_in, const int* in_sizes, int n_in,
                              void* d_out, int out_size, void* d_ws, size_t ws_size,
                              hipStream_t stream) {
    (void)in_sizes; (void)n_in; (void)out_size; (void)d_ws; (void)ws_size;
    const float* char_logits        = (const float*)d_in[0];
    const float* radical_logits     = (const float*)d_in[1];
    const float* structure          = (const float*)d_in[2];
    const float* stroke_count       = (const float*)d_in[3];
    const float* stroke_types       = (const float*)d_in[4];
    const int*   radical_mask       = (const int*)d_in[5];
    const int*   structure_label    = (const int*)d_in[6];
    const int*   stroke_count_label = (const int*)d_in[7];
    const float* stroke_type_sig    = (const float*)d_in[8];
    const float* W1                 = (const float*)d_in[9];
    const float* b1                 = (const float*)d_in[10];
    const float* W2                 = (const float*)d_in[11];
    const float* b2                 = (const float*)d_in[12];
    const float* rw                 = (const float*)d_in[13];
    float* out = (float*)d_out;

    reranker_kernel<<<NB, NT, 0, stream>>>(
        char_logits, radical_logits, structure, stroke_count, stroke_types,
        radical_mask, structure_label, stroke_count_label, stroke_type_sig,
        W1, b1, W2, b2, rw, out);
}